// Round 16
// baseline (440.682 us; speedup 1.0000x reference)
//
#include <hip/hip_runtime.h>
#include <hip/hip_bf16.h>
#include <math.h>

#define B_   2
#define L_   2048
#define D_   1024
#define H_   16
#define DK_  64
#define T_   4
#define F_   4096
#define NTOK (B_ * L_)   // 4096

typedef __bf16 bf16_t;
typedef bf16_t bf16x8 __attribute__((ext_vector_type(8)));
typedef float  f32x4  __attribute__((ext_vector_type(4)));
typedef unsigned short u16;
typedef u16 u16x8 __attribute__((ext_vector_type(8)));
typedef unsigned long long ull;

static __device__ __forceinline__ u16 f2b(float f) {
    __hip_bfloat16 h = __float2bfloat16(f);
    return *reinterpret_cast<u16*>(&h);
}
static __device__ __forceinline__ float b2f(u16 u) {
    __hip_bfloat16 h;
    *reinterpret_cast<u16*>(&h) = u;
    return __bfloat162float(h);
}

// async global->LDS, 16B per lane; LDS dest is linear (uniform base + lane*16)
static __device__ __forceinline__ void gld16(void* lds, const void* g) {
    __builtin_amdgcn_global_load_lds(
        (const __attribute__((address_space(1))) unsigned int*)g,
        (__attribute__((address_space(3))) unsigned int*)lds,
        16, 0, 0);
}

#define VMW(N) do { asm volatile("s_waitcnt vmcnt(" #N ")" ::: "memory"); \
                    __builtin_amdgcn_sched_barrier(0); } while (0)
#define BARR() do { __builtin_amdgcn_sched_barrier(0); \
                    __builtin_amdgcn_s_barrier();      \
                    __builtin_amdgcn_sched_barrier(0); } while (0)

// ---------------------------------------------------------------- cast x -> bf16
__global__ void k_cast_bf16(const float* __restrict__ in, u16* __restrict__ out, int n4) {
    int i = blockIdx.x * 256 + threadIdx.x;
    if (i >= n4) return;
    float4 v = reinterpret_cast<const float4*>(in)[i];
    ushort4 o;
    o.x = f2b(v.x); o.y = f2b(v.y); o.z = f2b(v.z); o.w = f2b(v.w);
    reinterpret_cast<ushort4*>(out)[i] = o;
}

// --------------------------------------------- transpose-cast W (KxN f32) -> Wt (NxK bf16)
// 64k x 32n tiles; packed u32 (2 bf16) writes.
__global__ void k_tcast(const float* __restrict__ W, u16* __restrict__ Wt,
                        int K, int N, long sW, long sWt) {
    __shared__ float tile[32][65];
    int z = blockIdx.z;
    W  += (long)z * sW;
    Wt += (long)z * sWt;
    int n0 = blockIdx.x * 32, k0 = blockIdx.y * 64;
    int tx = threadIdx.x, ty = threadIdx.y;   // block (32,8)
#pragma unroll
    for (int i = 0; i < 8; i++)
        tile[tx][ty + 8 * i] = W[(long)(k0 + ty + 8 * i) * N + n0 + tx];
    __syncthreads();
#pragma unroll
    for (int i = 0; i < 4; i++) {
        int n = ty + 8 * i;
        unsigned lo = f2b(tile[n][2 * tx]);
        unsigned hi = f2b(tile[n][2 * tx + 1]);
        reinterpret_cast<unsigned*>(Wt)[(((long)(n0 + n) * K + k0) >> 1) + tx] = lo | (hi << 16);
    }
}

// one launch for the five 1024x1024 weights (z selects)
__global__ void k_tcast5(const float* __restrict__ Wq, const float* __restrict__ Wk,
                         const float* __restrict__ Wv, const float* __restrict__ Wu,
                         const float* __restrict__ Wo, u16* __restrict__ WT,
                         u16* __restrict__ WOT) {
    __shared__ float tile[32][65];
    int z = blockIdx.z;
    const float* W;
    u16* Wt;
    if      (z == 0) { W = Wq; Wt = WT; }
    else if (z == 1) { W = Wk; Wt = WT + 1048576; }
    else if (z == 2) { W = Wv; Wt = WT + 2097152; }
    else if (z == 3) { W = Wu; Wt = WT + 3145728; }
    else             { W = Wo; Wt = WOT; }
    int n0 = blockIdx.x * 32, k0 = blockIdx.y * 64;
    int tx = threadIdx.x, ty = threadIdx.y;
#pragma unroll
    for (int i = 0; i < 8; i++)
        tile[tx][ty + 8 * i] = W[(long)(k0 + ty + 8 * i) * 1024 + n0 + tx];
    __syncthreads();
#pragma unroll
    for (int i = 0; i < 4; i++) {
        int n = ty + 8 * i;
        unsigned lo = f2b(tile[n][2 * tx]);
        unsigned hi = f2b(tile[n][2 * tx + 1]);
        reinterpret_cast<unsigned*>(Wt)[(((long)(n0 + n) * 1024 + k0) >> 1) + tx] = lo | (hi << 16);
    }
}

// ---------------------------------------------------------------- 128x128 4-wave GEMM v5
// (unchanged from round 15 -- 2 blocks/CU, 2-phase dbuf, counted vmcnt(8))
enum { EP_BF16 = 0, EP_F32 = 1, EP_GELU_BF16 = 2, EP_BIAS_F32 = 3 };

template <int MODE, bool AIDX, bool CIDX, bool GROUPED, bool VTOUT>
__global__ __launch_bounds__(256, 2)
void k_g2(const u16* __restrict__ A, const u16* __restrict__ Bt,
          void* __restrict__ Cv, u16* __restrict__ VTbuf,
          const float* __restrict__ bias,
          const int* __restrict__ idxb, const int* __restrict__ boff,
          const int* __restrict__ bcnt,
          int M, int K, int lda, int ldb, int ldc,
          long strideB, int biasStride)
{
    const int gx = gridDim.x;
    const int nwg = gx * gridDim.y;
    const int id = blockIdx.y * gx + blockIdx.x;
    const int q8 = nwg >> 3, r8 = nwg & 7, xcd = id & 7, sub = id >> 3;
    const int id2 = (xcd < r8 ? xcd * (q8 + 1) : r8 * (q8 + 1) + (xcd - r8) * q8) + sub;
    const int tm = id2 % gx, tn = id2 / gx;
    const int bm = tm * 128, bn = tn * 128;

    int pend = M;
    if (GROUPED) {
        bool dead = true;
        int g = 0;
#pragma unroll
        for (int t = 0; t < T_; t++) {
            int o = boff[t], c = bcnt[t];
            int pe = o + (((c + 127) >> 7) << 7);
            if (bm >= o && bm < pe) { g = t; pend = o + c; dead = false; }
        }
        if (dead) return;
        Bt += (long)g * strideB;
        bias += (long)g * biasStride;
    }

    const int tid = threadIdx.x;
    const int wid = tid >> 6, lane = tid & 63;
    const int lg = lane >> 4, lr = lane & 15;
    const int wr = wid >> 1, wc = wid & 1;

    __shared__ u16 lds[4 * 8192];   // 64KB

    const u16* gA[4];
    const u16* gB[4];
#pragma unroll
    for (int i = 0; i < 4; i++) {
        int s = tid + 256 * i;
        int row = s >> 3;
        int sch = (s & 7) ^ (row & 7);
        int pa = bm + row;
        if (GROUPED) pa = min(pa, pend - 1);
        long ra = AIDX ? (long)idxb[pa] : (long)pa;
        gA[i] = A + ra * lda + sch * 8;
        gB[i] = Bt + (long)(bn + row) * ldb + sch * 8;
    }
    auto STAGE = [&](u16* bufp, long ko) {
#pragma unroll
        for (int i = 0; i < 4; i++)
            gld16(bufp + (tid + 256 * i) * 8, gA[i] + ko);
#pragma unroll
        for (int i = 0; i < 4; i++)
            gld16(bufp + 8192 + (tid + 256 * i) * 8, gB[i] + ko);
    };

    int cko[2];
#pragma unroll
    for (int kk = 0; kk < 2; kk++) cko[kk] = ((4 * kk + lg) ^ (lr & 7)) * 8;
    int offA[4], offB[4];
#pragma unroll
    for (int i = 0; i < 4; i++) {
        offA[i] = (wr * 64 + i * 16 + lr) * 64;
        offB[i] = (wc * 64 + i * 16 + lr) * 64;
    }

    const f32x4 zero = {0.f, 0.f, 0.f, 0.f};
    f32x4 acc[4][4];
#pragma unroll
    for (int m = 0; m < 4; m++)
#pragma unroll
        for (int n = 0; n < 4; n++) acc[m][n] = zero;

    const int NT = K >> 6;

    STAGE(lds, 0);

    for (int t = 0; t < NT; t++) {
        u16* bb_ = lds + (t & 1) * 16384;
        u16* bnx = lds + ((t & 1) ^ 1) * 16384;
        if (t + 1 < NT) {
            STAGE(bnx, (long)(t + 1) * 64);
            VMW(8);
        } else {
            VMW(0);
        }
        BARR();

        bf16x8 av[4][2], bv[4][2];
#pragma unroll
        for (int i = 0; i < 4; i++)
#pragma unroll
            for (int kk = 0; kk < 2; kk++) {
                av[i][kk] = *reinterpret_cast<const bf16x8*>(bb_ + offA[i] + cko[kk]);
                bv[i][kk] = *reinterpret_cast<const bf16x8*>(bb_ + 8192 + offB[i] + cko[kk]);
            }
        __builtin_amdgcn_s_setprio(1);
#pragma unroll
        for (int kk = 0; kk < 2; kk++)
#pragma unroll
            for (int m = 0; m < 4; m++)
#pragma unroll
                for (int n = 0; n < 4; n++)
                    acc[m][n] = __builtin_amdgcn_mfma_f32_16x16x32_bf16(
                        av[m][kk], bv[n][kk], acc[m][n], 0, 0, 0);
        __builtin_amdgcn_s_setprio(0);
        BARR();
    }

    // ---- epilogue ----
    if (VTOUT && bn >= 2048 && bn < 3072) {
#pragma unroll
        for (int m = 0; m < 4; m++) {
            int tok0 = bm + wr * 64 + m * 16 + lg * 4;
            int bb2 = tok0 >> 11, tin = tok0 & 2047;
#pragma unroll
            for (int n = 0; n < 4; n++) {
                int gn = bn + wc * 64 + n * 16 + lr;
                int d = gn - 2048, hh = d >> 6, dk = d & 63;
                ushort4 o4;
                o4.x = f2b(acc[m][n][0]); o4.y = f2b(acc[m][n][1]);
                o4.z = f2b(acc[m][n][2]); o4.w = f2b(acc[m][n][3]);
                long vi = ((long)(bb2 * 16 + hh) * 64 + dk) * 2048 + tin;
                *reinterpret_cast<ushort4*>(VTbuf + vi) = o4;
            }
        }
        return;
    }
#pragma unroll
    for (int m = 0; m < 4; m++) {
#pragma unroll
        for (int r = 0; r < 4; r++) {
            int prow = bm + wr * 64 + m * 16 + lg * 4 + r;
            if (GROUPED && prow >= pend) continue;
            long crow = CIDX ? (long)idxb[prow] : (long)prow;
#pragma unroll
            for (int n = 0; n < 4; n++) {
                int gn = bn + wc * 64 + n * 16 + lr;
                float v = acc[m][n][r];
                long off = crow * (long)ldc + gn;
                if (MODE == EP_GELU_BF16) {
                    v += bias[gn];
                    v = 0.5f * v * (1.0f + erff(v * 0.70710678118654752f));
                }
                if (MODE == EP_BIAS_F32) v += bias[gn];
                if (MODE == EP_BF16 || MODE == EP_GELU_BF16)
                    ((u16*)Cv)[off] = f2b(v);
                else
                    ((float*)Cv)[off] = v;
            }
        }
    }
}

// ---------------------------------------------------------------- attention (v6)
// T14 async-stage: K/V for tile t+1 are global_load'ed into REGISTERS at the
// start of tile t's compute (HBM/L2 latency hides under QK^T+softmax+PV), then
// ds_write'n after the closing barrier (compiler emits counted per-register
// waits; by then the loads have landed). LDS stays single-buffered 48.5KB ->
// 3 blocks/CU co-residency preserved (dbuf LDS would drop it to 2).
// Same chunk-XOR swizzle both sides (write addr = old gld16 dest slot; source
// = old pre-swizzled addr). Ballots ride with the writes.
#define KVB 128
__global__ __launch_bounds__(256)
void k_attn(const u16* __restrict__ cat, const u16* __restrict__ VT,
            const int* __restrict__ types, const int* __restrict__ seql,
            u16* __restrict__ AG)
{
    const int qt = blockIdx.x, h = blockIdx.y, b = blockIdx.z;
    const int tid = threadIdx.x, w = tid >> 6, lane = tid & 63;
    const int lg = lane >> 4, lr = lane & 15;
    const int qbase = qt * 64;

    __shared__ u16 sK[KVB * 64];        // [key][dk], chunk = (c ^ (key&7))
    __shared__ u16 sV[64 * KVB];        // [dk][key], chunk = (c ^ (dk&15))
    __shared__ u16 sP[4 * 16 * KVB];    // per-wave [q][key], chunk = (c ^ q)
    __shared__ ull smask[4];

    const int seqlen = seql[b];
    const float QSC = 0.125f * 1.44269504f;
    const u16* vtb = VT + (long)(b * 16 + h) * 64 * 2048;

    // ---- staging addresses (pre-swizzled source; fixed LDS slot per thread) ----
    const u16* gK[4];
    const u16* gV[4];
    int dstK[4], dstV[4];
#pragma unroll
    for (int i = 0; i < 4; i++) {
        int c = tid + 256 * i;
        int rowK = c >> 3, slK = (c & 7) ^ (rowK & 7);
        gK[i] = cat + (long)(b * L_ + rowK) * 4096 + 1024 + h * 64 + slK * 8;
        dstK[i] = c * 8;
        int rowV = c >> 4, chV = c & 15, slV = chV ^ (rowV & 15);
        gV[i] = vtb + (long)rowV * 2048 + slV * 8;
        dstV[i] = c * 8;
    }
    u16x8 rk0, rk1, rk2, rk3, rv0, rv1, rv2, rv3;   // named (rule #20)
#define LOADKV(KB) do {                                                        \
    long koK = (long)(KB) * 4096, koV = (KB);                                  \
    rk0 = *reinterpret_cast<const u16x8*>(gK[0] + koK);                        \
    rk1 = *reinterpret_cast<const u16x8*>(gK[1] + koK);                        \
    rk2 = *reinterpret_cast<const u16x8*>(gK[2] + koK);                        \
    rk3 = *reinterpret_cast<const u16x8*>(gK[3] + koK);                        \
    rv0 = *reinterpret_cast<const u16x8*>(gV[0] + koV);                        \
    rv1 = *reinterpret_cast<const u16x8*>(gV[1] + koV);                        \
    rv2 = *reinterpret_cast<const u16x8*>(gV[2] + koV);                        \
    rv3 = *reinterpret_cast<const u16x8*>(gV[3] + koV);                        \
} while (0)
#define WRITEKV() do {                                                         \
    *reinterpret_cast<u16x8*>(sK + dstK[0]) = rk0;                             \
    *reinterpret_cast<u16x8*>(sK + dstK[1]) = rk1;                             \
    *reinterpret_cast<u16x8*>(sK + dstK[2]) = rk2;                             \
    *reinterpret_cast<u16x8*>(sK + dstK[3]) = rk3;                             \
    *reinterpret_cast<u16x8*>(sV + dstV[0]) = rv0;                             \
    *reinterpret_cast<u16x8*>(sV + dstV[1]) = rv1;                             \
    *reinterpret_cast<u16x8*>(sV + dstV[2]) = rv2;                             \
    *reinterpret_cast<u16x8*>(sV + dstV[3]) = rv3;                             \
} while (0)
#define BALLOTS(KB) do {                                                       \
    if (w < 2) {                                                               \
        int j = (KB) + w * 64 + lane;                                          \
        ull pm = __ballot(j >= seqlen);                                        \
        ull rm = __ballot(types[b * L_ + j] < 3);                              \
        if (lane == 0) { smask[w * 2] = pm; smask[w * 2 + 1] = rm; }           \
    }                                                                          \
} while (0)

    // Q fragments, pre-scaled to exp2 domain
    const long qrow = (long)(b * L_ + qbase + w * 16 + lr);
    const u16* qp = cat + qrow * 4096 + h * 64;
    bf16x8 qf0, qf1, onesv;
    {
        u16x8 a0 = *reinterpret_cast<const u16x8*>(qp + lg * 8);
        u16x8 a1 = *reinterpret_cast<const u16x8*>(qp + 32 + lg * 8);
#pragma unroll
        for (int e = 0; e < 8; e++) {
            qf0[e] = (bf16_t)(b2f(a0[e]) * QSC);
            qf1[e] = (bf16_t)(b2f(a1[e]) * QSC);
            onesv[e] = (bf16_t)1.0f;
        }
    }

    const f32x4 zero = {0.f, 0.f, 0.f, 0.f};
    f32x4 o[4] = {zero, zero, zero, zero};
    f32x4 lsum4 = zero;
    float mrow[4] = {-1e30f, -1e30f, -1e30f, -1e30f};

    const int nt = (seqlen + KVB - 1) / KVB;   // 8..16

    // prologue: tile 0 via registers -> LDS; masks; barrier
    LOADKV(0);
    WRITEKV();
    BALLOTS(0);
    __syncthreads();

    for (int ti = 0; ti < nt; ti++) {
        const int kb = ti * KVB;
        const bool s1 = (ti + 1 < nt);
        if (s1) {
            LOADKV(kb + KVB);                        // in flight across this tile's compute
            __builtin_amdgcn_sched_barrier(0);       // keep issue early
        }
        const ull pad0 = smask[0], pr0 = smask[1], pad1 = smask[2], pr1 = smask[3];

        // S = Q K^T  (16 q-rows x 128 keys per wave), exp2 domain
        f32x4 s[8];
#pragma unroll
        for (int n = 0; n < 8; n++) {
            int row = n * 16 + lr, r7 = row & 7;
            bf16x8 bk0 = *reinterpret_cast<const bf16x8*>(sK + row * 64 + ((lg ^ r7)) * 8);
            bf16x8 bk1 = *reinterpret_cast<const bf16x8*>(sK + row * 64 + (((lg ^ 4)) ^ r7) * 8);
            f32x4 t4 = zero;
            t4 = __builtin_amdgcn_mfma_f32_16x16x32_bf16(qf0, bk0, t4, 0, 0, 0);
            t4 = __builtin_amdgcn_mfma_f32_16x16x32_bf16(qf1, bk1, t4, 0, 0, 0);
            s[n] = t4;
        }

        // ---- masking with tile-class fast paths ----
        float tmax[4] = {-1e30f, -1e30f, -1e30f, -1e30f};
        const bool interior = (kb + KVB <= qbase) && (kb + KVB <= seqlen);
        const bool future   = (kb > qbase + 63);
        if (interior) {
#pragma unroll
            for (int n = 0; n < 8; n++)
#pragma unroll
                for (int r = 0; r < 4; r++) tmax[r] = fmaxf(tmax[r], s[n][r]);
        } else if (future) {
            const ull d0 = pad0 | ~pr0, d1 = pad1 | ~pr1;
#pragma unroll
            for (int n = 0; n < 8; n++) {
                bool dead = (((n < 4) ? d0 : d1) >> (((n & 3) * 16 + lr))) & 1ull;
#pragma unroll
                for (int r = 0; r < 4; r++) {
                    float sv = dead ? -1e30f : s[n][r];
                    s[n][r] = sv;
                    tmax[r] = fmaxf(tmax[r], sv);
                }
            }
        } else {
            ull dm0[4], dm1[4];
#pragma unroll
            for (int r = 0; r < 4; r++) {
                int d = qbase + w * 16 + 4 * lg + r - kb;
                ull h0 = (d < 0) ? ~0ull : ((d >= 63) ? 0ull : (~0ull << (d + 1)));
                ull h1 = (d < 64) ? ~0ull : ((d >= 127) ? 0ull : (~0ull << (d - 63)));
                dm0[r] = pad0 | (~pr0 & h0);
                dm1[r] = pad1 | (~pr1 & h1);
            }
#pragma unroll
            for (int n = 0; n < 8; n++) {
                int bp = (n & 3) * 16 + lr;
#pragma unroll
                for (int r = 0; r < 4; r++) {
                    bool dead = (((n < 4) ? dm0[r] : dm1[r]) >> bp) & 1ull;
                    float sv = dead ? -1e30f : s[n][r];
                    s[n][r] = sv;
                    tmax[r] = fmaxf(tmax[r], sv);
                }
            }
        }
        bool grew = (tmax[0] > mrow[0]) || (tmax[1] > mrow[1]) ||
                    (tmax[2] > mrow[2]) || (tmax[3] > mrow[3]);
        if (__any(grew)) {
#pragma unroll
            for (int r = 0; r < 4; r++) {
#pragma unroll
                for (int d = 1; d < 16; d <<= 1)
                    tmax[r] = fmaxf(tmax[r], __shfl_xor(tmax[r], d, 64));
            }
            float corr[4];
#pragma unroll
            for (int r = 0; r < 4; r++) {
                float mnew = fmaxf(mrow[r], tmax[r]);
                corr[r] = __builtin_amdgcn_exp2f(mrow[r] - mnew);
                mrow[r] = mnew;
                lsum4[r] *= corr[r];
            }
#pragma unroll
            for (int n2 = 0; n2 < 4; n2++) {
                f32x4 t4 = o[n2];
#pragma unroll
                for (int r = 0; r < 4; r++) t4[r] *= corr[r];
                o[n2] = t4;
            }
        }
#pragma unroll
        for (int n = 0; n < 8; n++)
#pragma unroll
            for (int r = 0; r < 4; r++)
                s[n][r] = __builtin_amdgcn_exp2f(s[n][r] - mrow[r]);
        // P -> LDS (per-wave region), swizzled write
        u16* Pw = sP + w * (16 * KVB);
#pragma unroll
        for (int n = 0; n < 8; n++) {
            int pc = n * 2 + (lr >> 3), p7 = lr & 7;
#pragma unroll
            for (int r = 0; r < 4; r++) {
                int q = 4 * lg + r;
                Pw[q * KVB + (pc ^ q) * 8 + p7] = f2b(s[n][r]);
            }
        }
        // PV + lsum (ones-trick)
        bf16x8 pa[4];
#pragma unroll
        for (int st = 0; st < 4; st++)
            pa[st] = *reinterpret_cast<const bf16x8*>(Pw + lr * KVB + ((st * 4 + lg) ^ lr) * 8);
#pragma unroll
        for (int st = 0; st < 4; st++)
            lsum4 = __builtin_amdgcn_mfma_f32_16x16x32_bf16(pa[st], onesv, lsum4, 0, 0, 0);
#pragma unroll
        for (int n2 = 0; n2 < 4; n2++) {
            int row = n2 * 16 + lr, r15 = row & 15;
            f32x4 t4 = o[n2];
#pragma unroll
            for (int st = 0; st < 4; st++) {
                bf16x8 vb = *reinterpret_cast<const bf16x8*>(sV + row * KVB + ((st * 4 + lg) ^ r15) * 8);
                t4 = __builtin_amdgcn_mfma_f32_16x16x32_bf16(pa[st], vb, t4, 0, 0, 0);
            }
            o[n2] = t4;
        }
        __syncthreads();             // all waves done with sK/sV/smask of tile ti
        if (s1) {
            WRITEKV();               // per-register waits; loads landed during compute
            BALLOTS(kb + KVB);
            __syncthreads();         // tile ti+1 + masks visible
        }
    }
    // epilogue: normalize, U-gate, store bf16
#pragma unroll
    for (int n2 = 0; n2 < 4; n2++) {
#pragma unroll
        for (int r = 0; r < 4; r++) {
            int ig = qbase + w * 16 + 4 * lg + r;
            long orow = (long)(b * L_ + ig);
            int j = n2 * 16 + lr;
            float u = b2f(cat[orow * 4096 + 3072 + h * 64 + j]);
            float val = o[n2][r] / lsum4[r] * u;
            AG[orow * 1024 + h * 64 + j] = f2b(val);
        }
    }
#undef LOADKV
#undef WRITEKV
#undef BALLOTS
}

// ---------------------------------------------------------------- layernorm (per token)
template <bool WB>
__global__ __launch_bounds__(256)
void k_ln(const float* __restrict__ xa, const float* __restrict__ ha,
          const float* __restrict__ g, const float* __restrict__ bb,
          const int* __restrict__ types,
          float* __restrict__ of, u16* __restrict__ ob)
{
    const int tok = blockIdx.x, tid = threadIdx.x;
    const long base = (long)tok * D_;
    float4 va = reinterpret_cast<const float4*>(xa + base)[tid];
    float4 vh = reinterpret_cast<const float4*>(ha + base)[tid];
    float v0 = va.x + vh.x, v1 = va.y + vh.y, v2 = va.z + vh.z, v3 = va.w + vh.w;
    float s = v0 + v1 + v2 + v3;
    float ss = v0 * v0 + v1 * v1 + v2 * v2 + v3 * v3;
#pragma unroll
    for (int d = 1; d < 64; d <<= 1) { s += __shfl_xor(s, d, 64); ss += __shfl_xor(ss, d, 64); }
    __shared__ float red[8];
    if ((tid & 63) == 0) { red[tid >> 6] = s; red[4 + (tid >> 6)] = ss; }
    __syncthreads();
    s  = red[0] + red[1] + red[2] + red[3];
    ss = red[4] + red[5] + red[6] + red[7];
    const float mu  = s * (1.f / D_);
    const float var = ss * (1.f / D_) - mu * mu;
    const float inv = rsqrtf(var + 1e-5f);
    const int t = types[tok];
    const float* gp = g + (long)t * D_ + tid * 4;
    const float* bp = bb + (long)t * D_ + tid * 4;
    float o0 = (v0 - mu) * inv * gp[0] + bp[0];
    float o1 = (v1 - mu) * inv * gp[1] + bp[1];
    float o2 = (v2 - mu) * inv * gp[2] + bp[2];
    float o3 = (v3 - mu) * inv * gp[3] + bp[3];
    reinterpret_cast<float4*>(of + base)[tid] = make_float4(o0, o1, o2, o3);
    if (WB) {
        ushort4 u4;
        u4.x = f2b(o0); u4.y = f2b(o1); u4.z = f2b(o2); u4.w = f2b(o3);
        reinterpret_cast<ushort4*>(ob + base)[tid] = u4;
    }
}

// ---------------------------------------------------------------- single-kernel bucketing
__global__ void k_bucket(const int* __restrict__ types, int* __restrict__ cnt,
                         int* __restrict__ off, int* __restrict__ idxb) {
    __shared__ int lc[4], lo[4], lcur[4];
    const int tid = threadIdx.x;
    if (tid < 4) lc[tid] = 0;
    __syncthreads();
    int ty[4];
#pragma unroll
    for (int i = 0; i < 4; i++) {
        ty[i] = types[tid + 1024 * i];
        atomicAdd(&lc[ty[i]], 1);
    }
    __syncthreads();
    if (tid == 0) {
        int a = 0;
        for (int t = 0; t < T_; t++) {
            lo[t] = a; lcur[t] = 0;
            a += ((lc[t] + 127) >> 7) << 7;
        }
    }
    __syncthreads();
#pragma unroll
    for (int i = 0; i < 4; i++) {
        int p = atomicAdd(&lcur[ty[i]], 1);
        idxb[lo[ty[i]] + p] = tid + 1024 * i;
    }
    if (tid < 4) { cnt[tid] = lc[tid]; off[tid] = lo[tid]; }
}

// ---------------------------------------------------------------- launch
extern "C" void kernel_launch(void* const* d_in, const int* in_sizes, int n_in,
                              void* d_out, int out_size, void* d_ws, size_t ws_size,
                              hipStream_t stream) {
    const float* x    = (const float*)d_in[0];
    const int* types  = (const int*)d_in[1];
    const int* seql   = (const int*)d_in[2];
    const float* Wq   = (const float*)d_in[3];
    const float* Wk   = (const float*)d_in[4];
    const float* Wv   = (const float*)d_in[5];
    const float* Wu   = (const float*)d_in[6];
    const float* Wo   = (const float*)d_in[7];
    const float* ln1g = (const float*)d_in[8];
    const float* ln1b = (const float*)d_in[9];
    const float* W1   = (const float*)d_in[10];
    const float* b1   = (const float*)d_in[11];
    const float* W2   = (const float*)d_in[12];
    const float* b2   = (const float*)d_in[13];
    const float* ln2g = (const float*)d_in[14];
    const float* ln2b = (const float*)d_in[15];

    char* ws = (char*)d_ws;
    constexpr size_t OFF_WT  = 0;
    constexpr size_t OFF_WOT = OFF_WT  + (size_t)4096 * 1024 * 2;
    constexpr size_t OFF_W1T = OFF_WOT + (size_t)1024 * 1024 * 2;
    constexpr size_t OFF_W2T = OFF_W1T + (size_t)T_ * 4096 * 1024 * 2;
    constexpr size_t OFF_XB  = OFF_W2T + (size_t)T_ * 4096 * 1024 * 2;   // x bf16 (later: AG)
    constexpr size_t OFF_CAT = OFF_XB  + (size_t)NTOK * D_ * 2;          // QKVU cat / Hidden
    constexpr size_t OFF_H   = OFF_CAT + (size_t)(NTOK + 512) * 4096 * 2; // VT (QKVU->attn), then h f32
    constexpr size_t OFF_X1  = OFF_H   + (size_t)NTOK * D_ * 4;
    constexpr size_t OFF_X1B = OFF_X1  + (size_t)NTOK * D_ * 4;
    constexpr size_t OFF_INT = OFF_X1B + (size_t)NTOK * D_ * 2;

    u16* WT   = (u16*)(ws + OFF_WT);
    u16* WOT  = (u16*)(ws + OFF_WOT);
    u16* W1T  = (u16*)(ws + OFF_W1T);
    u16* W2T  = (u16*)(ws + OFF_W2T);
    u16* XB   = (u16*)(ws + OFF_XB);      // also AG
    u16* CAT  = (u16*)(ws + OFF_CAT);     // also Hidden (padded positions)
    float* Hb = (float*)(ws + OFF_H);
    u16* VT   = (u16*)(ws + OFF_H);       // VT aliases Hb: live QKVU->attn only
    float* X1 = (float*)(ws + OFF_X1);
    u16* X1B  = (u16*)(ws + OFF_X1B);
    int* ibase = (int*)(ws + OFF_INT);    // cnt[4] off[4] idx[<=4608]
    int* cnt = ibase, *off = ibase + 4, *idxb = ibase + 8;

    dim3 blk(256), tb(32, 8);
    const int MT_PAD = 36;

    // 1. casts / transposes
    k_cast_bf16<<<NTOK * D_ / 4 / 256, blk, 0, stream>>>(x, XB, NTOK * D_ / 4);
    k_tcast5<<<dim3(32, 16, 5), tb, 0, stream>>>(Wq, Wk, Wv, Wu, Wo, WT, WOT);
    k_tcast<<<dim3(128, 16, T_), tb, 0, stream>>>(W1, W1T, 1024, 4096, (long)1024 * 4096, (long)4096 * 1024);
    k_tcast<<<dim3(32, 64, T_), tb, 0, stream>>>(W2, W2T, 4096, 1024, (long)4096 * 1024, (long)1024 * 4096);

    // 2. QKVU = x @ [Wq|Wk|Wv|Wu]; V-column blocks write transposed VT
    k_g2<EP_BF16, false, false, false, true><<<dim3(32, 32), blk, 0, stream>>>(
        XB, WT, CAT, VT, nullptr, nullptr, nullptr, nullptr,
        NTOK, 1024, 1024, 1024, 4096, 0, 0);

    // 3. attention -> gated output AG (reuses XB)
    k_attn<<<dim3(L_ / 64, H_, B_), blk, 0, stream>>>(CAT, VT, types, seql, XB);

    // 4. h = AG @ Wo (no split-K; overwrites Hb/VT -- attn done)
    k_g2<EP_F32, false, false, false, false><<<dim3(32, 8), blk, 0, stream>>>(
        XB, WOT, Hb, nullptr, nullptr, nullptr, nullptr, nullptr,
        NTOK, 1024, 1024, 1024, 1024, 0, 0);

    // 5. x1 = LN1(x + h)
    k_ln<true><<<NTOK, blk, 0, stream>>>(x, Hb, ln1g, ln1b, types, X1, X1B);

    // 6. bucket tokens (single kernel; 128-granular padded offsets)
    k_bucket<<<1, 1024, 0, stream>>>(types, cnt, off, idxb);

    // 7. Hidden = gelu(x1[idx] @ W1[t] + b1[t])  (grouped)
    k_g2<EP_GELU_BF16, true, false, true, false><<<dim3(MT_PAD, 32), blk, 0, stream>>>(
        X1B, W1T, CAT, nullptr, b1, idxb, off, cnt,
        NTOK, 1024, 1024, 1024, 4096, (long)4096 * 1024, 4096);

    // 8. h2 = Hidden @ W2[t] + b2[t]  (grouped, C scattered)
    k_g2<EP_BIAS_F32, false, true, true, false><<<dim3(MT_PAD, 8), blk, 0, stream>>>(
        CAT, W2T, Hb, nullptr, b2, idxb, off, cnt,
        NTOK, 4096, 4096, 4096, 1024, (long)1024 * 4096, 1024);

    // 9. out = LN2(x1 + h2)
    k_ln<false><<<NTOK, blk, 0, stream>>>(X1, Hb, ln2g, ln2b, types, (float*)d_out, nullptr);
}

// Round 17
// 385.118 us; speedup vs baseline: 1.1443x; 1.1443x over previous
//
#include <hip/hip_runtime.h>
#include <hip/hip_bf16.h>
#include <math.h>

#define B_   2
#define L_   2048
#define D_   1024
#define H_   16
#define DK_  64
#define T_   4
#define F_   4096
#define NTOK (B_ * L_)   // 4096

typedef __bf16 bf16_t;
typedef bf16_t bf16x8 __attribute__((ext_vector_type(8)));
typedef float  f32x4  __attribute__((ext_vector_type(4)));
typedef unsigned short u16;
typedef u16 u16x8 __attribute__((ext_vector_type(8)));
typedef unsigned long long ull;

static __device__ __forceinline__ u16 f2b(float f) {
    __hip_bfloat16 h = __float2bfloat16(f);
    return *reinterpret_cast<u16*>(&h);
}
static __device__ __forceinline__ float b2f(u16 u) {
    __hip_bfloat16 h;
    *reinterpret_cast<u16*>(&h) = u;
    return __bfloat162float(h);
}

// async global->LDS, 16B per lane; LDS dest is linear (uniform base + lane*16)
static __device__ __forceinline__ void gld16(void* lds, const void* g) {
    __builtin_amdgcn_global_load_lds(
        (const __attribute__((address_space(1))) unsigned int*)g,
        (__attribute__((address_space(3))) unsigned int*)lds,
        16, 0, 0);
}

#define VMW(N) do { asm volatile("s_waitcnt vmcnt(" #N ")" ::: "memory"); \
                    __builtin_amdgcn_sched_barrier(0); } while (0)
#define BARR() do { __builtin_amdgcn_sched_barrier(0); \
                    __builtin_amdgcn_s_barrier();      \
                    __builtin_amdgcn_sched_barrier(0); } while (0)

// ---------------------------------------------------------------- cast x -> bf16
__global__ void k_cast_bf16(const float* __restrict__ in, u16* __restrict__ out, int n4) {
    int i = blockIdx.x * 256 + threadIdx.x;
    if (i >= n4) return;
    float4 v = reinterpret_cast<const float4*>(in)[i];
    ushort4 o;
    o.x = f2b(v.x); o.y = f2b(v.y); o.z = f2b(v.z); o.w = f2b(v.w);
    reinterpret_cast<ushort4*>(out)[i] = o;
}

// --------------------------------------------- transpose-cast W (KxN f32) -> Wt (NxK bf16)
// 64k x 32n tiles; packed u32 (2 bf16) writes.
__global__ void k_tcast(const float* __restrict__ W, u16* __restrict__ Wt,
                        int K, int N, long sW, long sWt) {
    __shared__ float tile[32][65];
    int z = blockIdx.z;
    W  += (long)z * sW;
    Wt += (long)z * sWt;
    int n0 = blockIdx.x * 32, k0 = blockIdx.y * 64;
    int tx = threadIdx.x, ty = threadIdx.y;   // block (32,8)
#pragma unroll
    for (int i = 0; i < 8; i++)
        tile[tx][ty + 8 * i] = W[(long)(k0 + ty + 8 * i) * N + n0 + tx];
    __syncthreads();
#pragma unroll
    for (int i = 0; i < 4; i++) {
        int n = ty + 8 * i;
        unsigned lo = f2b(tile[n][2 * tx]);
        unsigned hi = f2b(tile[n][2 * tx + 1]);
        reinterpret_cast<unsigned*>(Wt)[(((long)(n0 + n) * K + k0) >> 1) + tx] = lo | (hi << 16);
    }
}

// one launch for the five 1024x1024 weights (z selects)
__global__ void k_tcast5(const float* __restrict__ Wq, const float* __restrict__ Wk,
                         const float* __restrict__ Wv, const float* __restrict__ Wu,
                         const float* __restrict__ Wo, u16* __restrict__ WT,
                         u16* __restrict__ WOT) {
    __shared__ float tile[32][65];
    int z = blockIdx.z;
    const float* W;
    u16* Wt;
    if      (z == 0) { W = Wq; Wt = WT; }
    else if (z == 1) { W = Wk; Wt = WT + 1048576; }
    else if (z == 2) { W = Wv; Wt = WT + 2097152; }
    else if (z == 3) { W = Wu; Wt = WT + 3145728; }
    else             { W = Wo; Wt = WOT; }
    int n0 = blockIdx.x * 32, k0 = blockIdx.y * 64;
    int tx = threadIdx.x, ty = threadIdx.y;
#pragma unroll
    for (int i = 0; i < 8; i++)
        tile[tx][ty + 8 * i] = W[(long)(k0 + ty + 8 * i) * 1024 + n0 + tx];
    __syncthreads();
#pragma unroll
    for (int i = 0; i < 4; i++) {
        int n = ty + 8 * i;
        unsigned lo = f2b(tile[n][2 * tx]);
        unsigned hi = f2b(tile[n][2 * tx + 1]);
        reinterpret_cast<unsigned*>(Wt)[(((long)(n0 + n) * 1024 + k0) >> 1) + tx] = lo | (hi << 16);
    }
}

// ---------------------------------------------------------------- 128x128 4-wave GEMM v5
// (unchanged -- 2 blocks/CU, 2-phase dbuf, counted vmcnt(8))
enum { EP_BF16 = 0, EP_F32 = 1, EP_GELU_BF16 = 2, EP_BIAS_F32 = 3 };

template <int MODE, bool AIDX, bool CIDX, bool GROUPED, bool VTOUT>
__global__ __launch_bounds__(256, 2)
void k_g2(const u16* __restrict__ A, const u16* __restrict__ Bt,
          void* __restrict__ Cv, u16* __restrict__ VTbuf,
          const float* __restrict__ bias,
          const int* __restrict__ idxb, const int* __restrict__ boff,
          const int* __restrict__ bcnt,
          int M, int K, int lda, int ldb, int ldc,
          long strideB, int biasStride)
{
    const int gx = gridDim.x;
    const int nwg = gx * gridDim.y;
    const int id = blockIdx.y * gx + blockIdx.x;
    const int q8 = nwg >> 3, r8 = nwg & 7, xcd = id & 7, sub = id >> 3;
    const int id2 = (xcd < r8 ? xcd * (q8 + 1) : r8 * (q8 + 1) + (xcd - r8) * q8) + sub;
    const int tm = id2 % gx, tn = id2 / gx;
    const int bm = tm * 128, bn = tn * 128;

    int pend = M;
    if (GROUPED) {
        bool dead = true;
        int g = 0;
#pragma unroll
        for (int t = 0; t < T_; t++) {
            int o = boff[t], c = bcnt[t];
            int pe = o + (((c + 127) >> 7) << 7);
            if (bm >= o && bm < pe) { g = t; pend = o + c; dead = false; }
        }
        if (dead) return;
        Bt += (long)g * strideB;
        bias += (long)g * biasStride;
    }

    const int tid = threadIdx.x;
    const int wid = tid >> 6, lane = tid & 63;
    const int lg = lane >> 4, lr = lane & 15;
    const int wr = wid >> 1, wc = wid & 1;

    __shared__ u16 lds[4 * 8192];   // 64KB

    const u16* gA[4];
    const u16* gB[4];
#pragma unroll
    for (int i = 0; i < 4; i++) {
        int s = tid + 256 * i;
        int row = s >> 3;
        int sch = (s & 7) ^ (row & 7);
        int pa = bm + row;
        if (GROUPED) pa = min(pa, pend - 1);
        long ra = AIDX ? (long)idxb[pa] : (long)pa;
        gA[i] = A + ra * lda + sch * 8;
        gB[i] = Bt + (long)(bn + row) * ldb + sch * 8;
    }
    auto STAGE = [&](u16* bufp, long ko) {
#pragma unroll
        for (int i = 0; i < 4; i++)
            gld16(bufp + (tid + 256 * i) * 8, gA[i] + ko);
#pragma unroll
        for (int i = 0; i < 4; i++)
            gld16(bufp + 8192 + (tid + 256 * i) * 8, gB[i] + ko);
    };

    int cko[2];
#pragma unroll
    for (int kk = 0; kk < 2; kk++) cko[kk] = ((4 * kk + lg) ^ (lr & 7)) * 8;
    int offA[4], offB[4];
#pragma unroll
    for (int i = 0; i < 4; i++) {
        offA[i] = (wr * 64 + i * 16 + lr) * 64;
        offB[i] = (wc * 64 + i * 16 + lr) * 64;
    }

    const f32x4 zero = {0.f, 0.f, 0.f, 0.f};
    f32x4 acc[4][4];
#pragma unroll
    for (int m = 0; m < 4; m++)
#pragma unroll
        for (int n = 0; n < 4; n++) acc[m][n] = zero;

    const int NT = K >> 6;

    STAGE(lds, 0);

    for (int t = 0; t < NT; t++) {
        u16* bb_ = lds + (t & 1) * 16384;
        u16* bnx = lds + ((t & 1) ^ 1) * 16384;
        if (t + 1 < NT) {
            STAGE(bnx, (long)(t + 1) * 64);
            VMW(8);
        } else {
            VMW(0);
        }
        BARR();

        bf16x8 av[4][2], bv[4][2];
#pragma unroll
        for (int i = 0; i < 4; i++)
#pragma unroll
            for (int kk = 0; kk < 2; kk++) {
                av[i][kk] = *reinterpret_cast<const bf16x8*>(bb_ + offA[i] + cko[kk]);
                bv[i][kk] = *reinterpret_cast<const bf16x8*>(bb_ + 8192 + offB[i] + cko[kk]);
            }
        __builtin_amdgcn_s_setprio(1);
#pragma unroll
        for (int kk = 0; kk < 2; kk++)
#pragma unroll
            for (int m = 0; m < 4; m++)
#pragma unroll
                for (int n = 0; n < 4; n++)
                    acc[m][n] = __builtin_amdgcn_mfma_f32_16x16x32_bf16(
                        av[m][kk], bv[n][kk], acc[m][n], 0, 0, 0);
        __builtin_amdgcn_s_setprio(0);
        BARR();
    }

    // ---- epilogue ----
    if (VTOUT && bn >= 2048 && bn < 3072) {
#pragma unroll
        for (int m = 0; m < 4; m++) {
            int tok0 = bm + wr * 64 + m * 16 + lg * 4;
            int bb2 = tok0 >> 11, tin = tok0 & 2047;
#pragma unroll
            for (int n = 0; n < 4; n++) {
                int gn = bn + wc * 64 + n * 16 + lr;
                int d = gn - 2048, hh = d >> 6, dk = d & 63;
                ushort4 o4;
                o4.x = f2b(acc[m][n][0]); o4.y = f2b(acc[m][n][1]);
                o4.z = f2b(acc[m][n][2]); o4.w = f2b(acc[m][n][3]);
                long vi = ((long)(bb2 * 16 + hh) * 64 + dk) * 2048 + tin;
                *reinterpret_cast<ushort4*>(VTbuf + vi) = o4;
            }
        }
        return;
    }
#pragma unroll
    for (int m = 0; m < 4; m++) {
#pragma unroll
        for (int r = 0; r < 4; r++) {
            int prow = bm + wr * 64 + m * 16 + lg * 4 + r;
            if (GROUPED && prow >= pend) continue;
            long crow = CIDX ? (long)idxb[prow] : (long)prow;
#pragma unroll
            for (int n = 0; n < 4; n++) {
                int gn = bn + wc * 64 + n * 16 + lr;
                float v = acc[m][n][r];
                long off = crow * (long)ldc + gn;
                if (MODE == EP_GELU_BF16) {
                    v += bias[gn];
                    v = 0.5f * v * (1.0f + erff(v * 0.70710678118654752f));
                }
                if (MODE == EP_BIAS_F32) v += bias[gn];
                if (MODE == EP_BF16 || MODE == EP_GELU_BF16)
                    ((u16*)Cv)[off] = f2b(v);
                else
                    ((float*)Cv)[off] = v;
            }
        }
    }
}

// ---------------------------------------------------------------- attention (v5r + T5)
// Round-15 staging restored (gld16 + single drain per tile: 120 VGPR, 3 blocks/CU
// -- round-16's register prefetch crossed the 128-VGPR cliff and halved occupancy).
// Added: s_setprio(1) around MFMA clusters (m191 regime: independent co-resident
// blocks at different phases per CU).
#define KVB 128
__global__ __launch_bounds__(256)
void k_attn(const u16* __restrict__ cat, const u16* __restrict__ VT,
            const int* __restrict__ types, const int* __restrict__ seql,
            u16* __restrict__ AG)
{
    const int qt = blockIdx.x, h = blockIdx.y, b = blockIdx.z;
    const int tid = threadIdx.x, w = tid >> 6, lane = tid & 63;
    const int lg = lane >> 4, lr = lane & 15;
    const int qbase = qt * 64;

    __shared__ u16 sK[KVB * 64];
    __shared__ u16 sV[64 * KVB];
    __shared__ u16 sP[4 * 16 * KVB];
    __shared__ ull smask[4];

    const int seqlen = seql[b];
    const float QSC = 0.125f * 1.44269504f;
    const u16* vtb = VT + (long)(b * 16 + h) * 64 * 2048;

    const long qrow = (long)(b * L_ + qbase + w * 16 + lr);
    const u16* qp = cat + qrow * 4096 + h * 64;
    bf16x8 qf0, qf1, onesv;
    {
        u16x8 a0 = *reinterpret_cast<const u16x8*>(qp + lg * 8);
        u16x8 a1 = *reinterpret_cast<const u16x8*>(qp + 32 + lg * 8);
#pragma unroll
        for (int e = 0; e < 8; e++) {
            qf0[e] = (bf16_t)(b2f(a0[e]) * QSC);
            qf1[e] = (bf16_t)(b2f(a1[e]) * QSC);
            onesv[e] = (bf16_t)1.0f;
        }
    }

    const f32x4 zero = {0.f, 0.f, 0.f, 0.f};
    f32x4 o[4] = {zero, zero, zero, zero};
    f32x4 lsum4 = zero;
    float mrow[4] = {-1e30f, -1e30f, -1e30f, -1e30f};

    for (int kb = 0; kb < L_; kb += KVB) {
        if (kb >= seqlen) break;
#pragma unroll
        for (int i = 0; i < 4; i++) {
            int c = tid + 256 * i;
            int row = c >> 3, sl = (c & 7) ^ (row & 7);
            gld16(sK + c * 8, cat + (long)(b * L_ + kb + row) * 4096 + 1024 + h * 64 + sl * 8);
        }
#pragma unroll
        for (int i = 0; i < 4; i++) {
            int c = tid + 256 * i;
            int row = c >> 4, ch = c & 15;
            int sl = ch ^ (row & 15);
            gld16(sV + c * 8, vtb + (long)row * 2048 + kb + sl * 8);
        }
        if (w < 2) {
            int j = kb + w * 64 + lane;
            ull pm = __ballot(j >= seqlen);
            ull rm = __ballot(types[b * L_ + j] < 3);
            if (lane == 0) { smask[w * 2] = pm; smask[w * 2 + 1] = rm; }
        }
        __syncthreads();
        const ull pad0 = smask[0], pr0 = smask[1], pad1 = smask[2], pr1 = smask[3];

        f32x4 s[8];
#pragma unroll
        for (int n = 0; n < 8; n++) {
            int row = n * 16 + lr, r7 = row & 7;
            bf16x8 bk0 = *reinterpret_cast<const bf16x8*>(sK + row * 64 + ((lg ^ r7)) * 8);
            bf16x8 bk1 = *reinterpret_cast<const bf16x8*>(sK + row * 64 + (((lg ^ 4)) ^ r7) * 8);
            f32x4 t4 = zero;
            __builtin_amdgcn_s_setprio(1);
            t4 = __builtin_amdgcn_mfma_f32_16x16x32_bf16(qf0, bk0, t4, 0, 0, 0);
            t4 = __builtin_amdgcn_mfma_f32_16x16x32_bf16(qf1, bk1, t4, 0, 0, 0);
            __builtin_amdgcn_s_setprio(0);
            s[n] = t4;
        }

        float tmax[4] = {-1e30f, -1e30f, -1e30f, -1e30f};
        const bool interior = (kb + KVB <= qbase) && (kb + KVB <= seqlen);
        const bool future   = (kb > qbase + 63);
        if (interior) {
#pragma unroll
            for (int n = 0; n < 8; n++)
#pragma unroll
                for (int r = 0; r < 4; r++) tmax[r] = fmaxf(tmax[r], s[n][r]);
        } else if (future) {
            const ull d0 = pad0 | ~pr0, d1 = pad1 | ~pr1;
#pragma unroll
            for (int n = 0; n < 8; n++) {
                bool dead = (((n < 4) ? d0 : d1) >> (((n & 3) * 16 + lr))) & 1ull;
#pragma unroll
                for (int r = 0; r < 4; r++) {
                    float sv = dead ? -1e30f : s[n][r];
                    s[n][r] = sv;
                    tmax[r] = fmaxf(tmax[r], sv);
                }
            }
        } else {
            ull dm0[4], dm1[4];
#pragma unroll
            for (int r = 0; r < 4; r++) {
                int d = qbase + w * 16 + 4 * lg + r - kb;
                ull h0 = (d < 0) ? ~0ull : ((d >= 63) ? 0ull : (~0ull << (d + 1)));
                ull h1 = (d < 64) ? ~0ull : ((d >= 127) ? 0ull : (~0ull << (d - 63)));
                dm0[r] = pad0 | (~pr0 & h0);
                dm1[r] = pad1 | (~pr1 & h1);
            }
#pragma unroll
            for (int n = 0; n < 8; n++) {
                int bp = (n & 3) * 16 + lr;
#pragma unroll
                for (int r = 0; r < 4; r++) {
                    bool dead = (((n < 4) ? dm0[r] : dm1[r]) >> bp) & 1ull;
                    float sv = dead ? -1e30f : s[n][r];
                    s[n][r] = sv;
                    tmax[r] = fmaxf(tmax[r], sv);
                }
            }
        }
        bool grew = (tmax[0] > mrow[0]) || (tmax[1] > mrow[1]) ||
                    (tmax[2] > mrow[2]) || (tmax[3] > mrow[3]);
        if (__any(grew)) {
#pragma unroll
            for (int r = 0; r < 4; r++) {
#pragma unroll
                for (int d = 1; d < 16; d <<= 1)
                    tmax[r] = fmaxf(tmax[r], __shfl_xor(tmax[r], d, 64));
            }
            float corr[4];
#pragma unroll
            for (int r = 0; r < 4; r++) {
                float mnew = fmaxf(mrow[r], tmax[r]);
                corr[r] = __builtin_amdgcn_exp2f(mrow[r] - mnew);
                mrow[r] = mnew;
                lsum4[r] *= corr[r];
            }
#pragma unroll
            for (int n2 = 0; n2 < 4; n2++) {
                f32x4 t4 = o[n2];
#pragma unroll
                for (int r = 0; r < 4; r++) t4[r] *= corr[r];
                o[n2] = t4;
            }
        }
#pragma unroll
        for (int n = 0; n < 8; n++)
#pragma unroll
            for (int r = 0; r < 4; r++)
                s[n][r] = __builtin_amdgcn_exp2f(s[n][r] - mrow[r]);
        u16* Pw = sP + w * (16 * KVB);
#pragma unroll
        for (int n = 0; n < 8; n++) {
            int pc = n * 2 + (lr >> 3), p7 = lr & 7;
#pragma unroll
            for (int r = 0; r < 4; r++) {
                int q = 4 * lg + r;
                Pw[q * KVB + (pc ^ q) * 8 + p7] = f2b(s[n][r]);
            }
        }
        bf16x8 pa[4];
#pragma unroll
        for (int st = 0; st < 4; st++)
            pa[st] = *reinterpret_cast<const bf16x8*>(Pw + lr * KVB + ((st * 4 + lg) ^ lr) * 8);
        __builtin_amdgcn_s_setprio(1);
#pragma unroll
        for (int st = 0; st < 4; st++)
            lsum4 = __builtin_amdgcn_mfma_f32_16x16x32_bf16(pa[st], onesv, lsum4, 0, 0, 0);
        __builtin_amdgcn_s_setprio(0);
#pragma unroll
        for (int n2 = 0; n2 < 4; n2++) {
            int row = n2 * 16 + lr, r15 = row & 15;
            f32x4 t4 = o[n2];
            bf16x8 vb0 = *reinterpret_cast<const bf16x8*>(sV + row * KVB + ((0 * 4 + lg) ^ r15) * 8);
            bf16x8 vb1 = *reinterpret_cast<const bf16x8*>(sV + row * KVB + ((1 * 4 + lg) ^ r15) * 8);
            bf16x8 vb2 = *reinterpret_cast<const bf16x8*>(sV + row * KVB + ((2 * 4 + lg) ^ r15) * 8);
            bf16x8 vb3 = *reinterpret_cast<const bf16x8*>(sV + row * KVB + ((3 * 4 + lg) ^ r15) * 8);
            __builtin_amdgcn_s_setprio(1);
            t4 = __builtin_amdgcn_mfma_f32_16x16x32_bf16(pa[0], vb0, t4, 0, 0, 0);
            t4 = __builtin_amdgcn_mfma_f32_16x16x32_bf16(pa[1], vb1, t4, 0, 0, 0);
            t4 = __builtin_amdgcn_mfma_f32_16x16x32_bf16(pa[2], vb2, t4, 0, 0, 0);
            t4 = __builtin_amdgcn_mfma_f32_16x16x32_bf16(pa[3], vb3, t4, 0, 0, 0);
            __builtin_amdgcn_s_setprio(0);
            o[n2] = t4;
        }
        __syncthreads();
    }
#pragma unroll
    for (int n2 = 0; n2 < 4; n2++) {
#pragma unroll
        for (int r = 0; r < 4; r++) {
            int ig = qbase + w * 16 + 4 * lg + r;
            long orow = (long)(b * L_ + ig);
            int j = n2 * 16 + lr;
            float u = b2f(cat[orow * 4096 + 3072 + h * 64 + j]);
            float val = o[n2][r] / lsum4[r] * u;
            AG[orow * 1024 + h * 64 + j] = f2b(val);
        }
    }
}

// ---------------------------------------------------------------- layernorm (per token)
template <bool WB>
__global__ __launch_bounds__(256)
void k_ln(const float* __restrict__ xa, const float* __restrict__ ha,
          const float* __restrict__ g, const float* __restrict__ bb,
          const int* __restrict__ types,
          float* __restrict__ of, u16* __restrict__ ob)
{
    const int tok = blockIdx.x, tid = threadIdx.x;
    const long base = (long)tok * D_;
    float4 va = reinterpret_cast<const float4*>(xa + base)[tid];
    float4 vh = reinterpret_cast<const float4*>(ha + base)[tid];
    float v0 = va.x + vh.x, v1 = va.y + vh.y, v2 = va.z + vh.z, v3 = va.w + vh.w;
    float s = v0 + v1 + v2 + v3;
    float ss = v0 * v0 + v1 * v1 + v2 * v2 + v3 * v3;
#pragma unroll
    for (int d = 1; d < 64; d <<= 1) { s += __shfl_xor(s, d, 64); ss += __shfl_xor(ss, d, 64); }
    __shared__ float red[8];
    if ((tid & 63) == 0) { red[tid >> 6] = s; red[4 + (tid >> 6)] = ss; }
    __syncthreads();
    s  = red[0] + red[1] + red[2] + red[3];
    ss = red[4] + red[5] + red[6] + red[7];
    const float mu  = s * (1.f / D_);
    const float var = ss * (1.f / D_) - mu * mu;
    const float inv = rsqrtf(var + 1e-5f);
    const int t = types[tok];
    const float* gp = g + (long)t * D_ + tid * 4;
    const float* bp = bb + (long)t * D_ + tid * 4;
    float o0 = (v0 - mu) * inv * gp[0] + bp[0];
    float o1 = (v1 - mu) * inv * gp[1] + bp[1];
    float o2 = (v2 - mu) * inv * gp[2] + bp[2];
    float o3 = (v3 - mu) * inv * gp[3] + bp[3];
    reinterpret_cast<float4*>(of + base)[tid] = make_float4(o0, o1, o2, o3);
    if (WB) {
        ushort4 u4;
        u4.x = f2b(o0); u4.y = f2b(o1); u4.z = f2b(o2); u4.w = f2b(o3);
        reinterpret_cast<ushort4*>(ob + base)[tid] = u4;
    }
}

// ---------------------------------------------------------------- single-kernel bucketing
__global__ void k_bucket(const int* __restrict__ types, int* __restrict__ cnt,
                         int* __restrict__ off, int* __restrict__ idxb) {
    __shared__ int lc[4], lo[4], lcur[4];
    const int tid = threadIdx.x;
    if (tid < 4) lc[tid] = 0;
    __syncthreads();
    int ty[4];
#pragma unroll
    for (int i = 0; i < 4; i++) {
        ty[i] = types[tid + 1024 * i];
        atomicAdd(&lc[ty[i]], 1);
    }
    __syncthreads();
    if (tid == 0) {
        int a = 0;
        for (int t = 0; t < T_; t++) {
            lo[t] = a; lcur[t] = 0;
            a += ((lc[t] + 127) >> 7) << 7;
        }
    }
    __syncthreads();
#pragma unroll
    for (int i = 0; i < 4; i++) {
        int p = atomicAdd(&lcur[ty[i]], 1);
        idxb[lo[ty[i]] + p] = tid + 1024 * i;
    }
    if (tid < 4) { cnt[tid] = lc[tid]; off[tid] = lo[tid]; }
}

// ---------------------------------------------------------------- launch
extern "C" void kernel_launch(void* const* d_in, const int* in_sizes, int n_in,
                              void* d_out, int out_size, void* d_ws, size_t ws_size,
                              hipStream_t stream) {
    const float* x    = (const float*)d_in[0];
    const int* types  = (const int*)d_in[1];
    const int* seql   = (const int*)d_in[2];
    const float* Wq   = (const float*)d_in[3];
    const float* Wk   = (const float*)d_in[4];
    const float* Wv   = (const float*)d_in[5];
    const float* Wu   = (const float*)d_in[6];
    const float* Wo   = (const float*)d_in[7];
    const float* ln1g = (const float*)d_in[8];
    const float* ln1b = (const float*)d_in[9];
    const float* W1   = (const float*)d_in[10];
    const float* b1   = (const float*)d_in[11];
    const float* W2   = (const float*)d_in[12];
    const float* b2   = (const float*)d_in[13];
    const float* ln2g = (const float*)d_in[14];
    const float* ln2b = (const float*)d_in[15];

    char* ws = (char*)d_ws;
    constexpr size_t OFF_WT  = 0;
    constexpr size_t OFF_WOT = OFF_WT  + (size_t)4096 * 1024 * 2;
    constexpr size_t OFF_W1T = OFF_WOT + (size_t)1024 * 1024 * 2;
    constexpr size_t OFF_W2T = OFF_W1T + (size_t)T_ * 4096 * 1024 * 2;
    constexpr size_t OFF_XB  = OFF_W2T + (size_t)T_ * 4096 * 1024 * 2;   // x bf16 (later: AG)
    constexpr size_t OFF_CAT = OFF_XB  + (size_t)NTOK * D_ * 2;          // QKVU cat / Hidden
    constexpr size_t OFF_H   = OFF_CAT + (size_t)(NTOK + 512) * 4096 * 2; // VT (QKVU->attn), then h f32
    constexpr size_t OFF_X1  = OFF_H   + (size_t)NTOK * D_ * 4;
    constexpr size_t OFF_X1B = OFF_X1  + (size_t)NTOK * D_ * 4;
    constexpr size_t OFF_INT = OFF_X1B + (size_t)NTOK * D_ * 2;

    u16* WT   = (u16*)(ws + OFF_WT);
    u16* WOT  = (u16*)(ws + OFF_WOT);
    u16* W1T  = (u16*)(ws + OFF_W1T);
    u16* W2T  = (u16*)(ws + OFF_W2T);
    u16* XB   = (u16*)(ws + OFF_XB);      // also AG
    u16* CAT  = (u16*)(ws + OFF_CAT);     // also Hidden (padded positions)
    float* Hb = (float*)(ws + OFF_H);
    u16* VT   = (u16*)(ws + OFF_H);       // VT aliases Hb: live QKVU->attn only
    float* X1 = (float*)(ws + OFF_X1);
    u16* X1B  = (u16*)(ws + OFF_X1B);
    int* ibase = (int*)(ws + OFF_INT);    // cnt[4] off[4] idx[<=4608]
    int* cnt = ibase, *off = ibase + 4, *idxb = ibase + 8;

    dim3 blk(256), tb(32, 8);
    const int MT_PAD = 36;

    // 1. casts / transposes
    k_cast_bf16<<<NTOK * D_ / 4 / 256, blk, 0, stream>>>(x, XB, NTOK * D_ / 4);
    k_tcast5<<<dim3(32, 16, 5), tb, 0, stream>>>(Wq, Wk, Wv, Wu, Wo, WT, WOT);
    k_tcast<<<dim3(128, 16, T_), tb, 0, stream>>>(W1, W1T, 1024, 4096, (long)1024 * 4096, (long)4096 * 1024);
    k_tcast<<<dim3(32, 64, T_), tb, 0, stream>>>(W2, W2T, 4096, 1024, (long)4096 * 1024, (long)1024 * 4096);

    // 2. QKVU = x @ [Wq|Wk|Wv|Wu]; V-column blocks write transposed VT
    k_g2<EP_BF16, false, false, false, true><<<dim3(32, 32), blk, 0, stream>>>(
        XB, WT, CAT, VT, nullptr, nullptr, nullptr, nullptr,
        NTOK, 1024, 1024, 1024, 4096, 0, 0);

    // 3. attention -> gated output AG (reuses XB)
    k_attn<<<dim3(L_ / 64, H_, B_), blk, 0, stream>>>(CAT, VT, types, seql, XB);

    // 4. h = AG @ Wo (no split-K; overwrites Hb/VT -- attn done)
    k_g2<EP_F32, false, false, false, false><<<dim3(32, 8), blk, 0, stream>>>(
        XB, WOT, Hb, nullptr, nullptr, nullptr, nullptr, nullptr,
        NTOK, 1024, 1024, 1024, 1024, 0, 0);

    // 5. x1 = LN1(x + h)
    k_ln<true><<<NTOK, blk, 0, stream>>>(x, Hb, ln1g, ln1b, types, X1, X1B);

    // 6. bucket tokens (single kernel; 128-granular padded offsets)
    k_bucket<<<1, 1024, 0, stream>>>(types, cnt, off, idxb);

    // 7. Hidden = gelu(x1[idx] @ W1[t] + b1[t])  (grouped)
    k_g2<EP_GELU_BF16, true, false, true, false><<<dim3(MT_PAD, 32), blk, 0, stream>>>(
        X1B, W1T, CAT, nullptr, b1, idxb, off, cnt,
        NTOK, 1024, 1024, 1024, 4096, (long)4096 * 1024, 4096);

    // 8. h2 = Hidden @ W2[t] + b2[t]  (grouped, C scattered)
    k_g2<EP_BIAS_F32, false, true, true, false><<<dim3(MT_PAD, 8), blk, 0, stream>>>(
        CAT, W2T, Hb, nullptr, b2, idxb, off, cnt,
        NTOK, 4096, 4096, 4096, 1024, (long)1024 * 4096, 1024);

    // 9. out = LN2(x1 + h2)
    k_ln<false><<<NTOK, blk, 0, stream>>>(X1, Hb, ln2g, ln2b, types, (float*)d_out, nullptr);
}